// Round 1
// baseline (314.969 us; speedup 1.0000x reference)
//
#include <hip/hip_runtime.h>

#define N_NODES 10000
#define N_EDGES 160000
#define MUL0 16
#define MUL1 8
#define H_EDGE 64
#define W_NUMEL 576
#define EPS 1e-5f

#define BM 32          // edges per block
#define THREADS 256

#define INV16 0.25f
#define INV24 0.20412414523193154f   // 1/sqrt(24)
#define INV8  0.3535533905932738f    // 1/sqrt(8)

// -----------------------------------------------------------------------------
// Fused: h = relu(ef@W1+b1); w = h@W2+b2; tp = tensor_product(x[dst], sh, w);
// atomic scatter into sums[src], cnts[src].
// LDS: W1s 16KB + Hs 8.3KB + A 36.9KB (A reused: ef-tile -> W2 k-chunks -> w-tile)
// -----------------------------------------------------------------------------
__global__ __launch_bounds__(THREADS, 2)
void fused_edge_kernel(const float* __restrict__ atom,   // [N_NODES*40]
                       const float* __restrict__ ef,     // [N_EDGES*64]
                       const float* __restrict__ esh,    // [N_EDGES*4]
                       const int*   __restrict__ e_dst,  // [N_EDGES]
                       const int*   __restrict__ e_src,  // [N_EDGES]
                       const float* __restrict__ W1,     // [64*64]
                       const float* __restrict__ b1,     // [64]
                       const float* __restrict__ W2,     // [64*576]
                       const float* __restrict__ b2,     // [576]
                       float* __restrict__ sums,         // [N_NODES*40]
                       float* __restrict__ cnts)         // [N_NODES]
{
    __shared__ __align__(16) float W1s[64 * 64];      // W1[k][c]
    __shared__ __align__(16) float Hs[BM * 65];       // padded (+1) h tile
    __shared__ __align__(16) float A[16 * 576];       // ef-tile / W2-chunk / w-tile

    const int tid = threadIdx.x;
    const int e0  = blockIdx.x * BM;

    // ---- load W1 (4096 f) and ef tile (2048 f, into A region) ----
    {
        const float4* g = (const float4*)W1;
        float4* s = (float4*)W1s;
        #pragma unroll
        for (int r = 0; r < 4; ++r) s[r * 256 + tid] = g[r * 256 + tid];
        const float4* ge = (const float4*)(ef + (size_t)e0 * 64);
        float4* se = (float4*)A;
        #pragma unroll
        for (int r = 0; r < 2; ++r) se[r * 256 + tid] = ge[r * 256 + tid];
    }
    __syncthreads();

    // ---- GEMM1: Hs = relu(ef @ W1 + b1), 32 x 64 ----
    {
        const int c  = tid & 63;
        const int le = tid >> 6;           // 0..3, edges {le, le+4, ..., le+28}
        float acc1[8];
        const float bb = b1[c];
        #pragma unroll
        for (int q = 0; q < 8; ++q) acc1[q] = bb;
        const float* efs = A;
        for (int k = 0; k < 64; ++k) {
            const float wv = W1s[k * 64 + c];
            #pragma unroll
            for (int q = 0; q < 8; ++q)
                acc1[q] = fmaf(efs[(le + 4 * q) * 64 + k], wv, acc1[q]);
        }
        #pragma unroll
        for (int q = 0; q < 8; ++q)
            Hs[(le + 4 * q) * 65 + c] = fmaxf(acc1[q], 0.0f);
    }
    __syncthreads();

    // ---- GEMM2: w = h @ W2 + b2 ; acc[8 edges][9 cols] per thread ----
    const int eg = tid & 3;                // edges {eg, eg+4, ..., eg+28}
    const int jg = tid >> 2;               // 0..63, cols [jg*9, jg*9+9)
    float acc[8][9];
    #pragma unroll
    for (int q = 0; q < 8; ++q)
        #pragma unroll
        for (int jj = 0; jj < 9; ++jj) acc[q][jj] = 0.0f;

    for (int kt = 0; kt < 4; ++kt) {
        // load W2 rows [kt*16, kt*16+16) -> A (9216 floats)
        {
            const float4* g = (const float4*)W2 + kt * 2304;
            float4* s = (float4*)A;
            #pragma unroll
            for (int r = 0; r < 9; ++r) s[r * 256 + tid] = g[r * 256 + tid];
        }
        __syncthreads();
        #pragma unroll 4
        for (int kk = 0; kk < 16; ++kk) {
            float hreg[8];
            #pragma unroll
            for (int q = 0; q < 8; ++q)
                hreg[q] = Hs[(eg + 4 * q) * 65 + kt * 16 + kk];
            #pragma unroll
            for (int jj = 0; jj < 9; ++jj) {
                const float av = A[kk * 576 + jg * 9 + jj];
                #pragma unroll
                for (int q = 0; q < 8; ++q)
                    acc[q][jj] = fmaf(hreg[q], av, acc[q][jj]);
            }
        }
        __syncthreads();
    }

    // ---- TP + scatter, two halves of 16 edges (w-tile reuses A) ----
    for (int half = 0; half < 2; ++half) {
        __syncthreads();   // protect previous A readers
        #pragma unroll
        for (int qq = 0; qq < 4; ++qq) {
            const int q  = half * 4 + qq;
            const int el = eg + 4 * qq;            // local edge in [0,16)
            #pragma unroll
            for (int jj = 0; jj < 9; ++jj)
                A[el * 576 + jg * 9 + jj] = acc[q][jj] + b2[jg * 9 + jj];
        }
        __syncthreads();

        const int r  = tid & 15;
        const int el = tid >> 4;                   // 0..15
        const int e  = e0 + half * 16 + el;
        const int dst = e_dst[e];
        const int src = e_src[e];
        const float* x = atom + (size_t)dst * 40;
        const float sh0 = esh[e * 4 + 0];
        const float s1x = esh[e * 4 + 1];
        const float s1y = esh[e * 4 + 2];
        const float s1z = esh[e * 4 + 3];
        const float* Ae = A + el * 576;

        // out0[r] = INV16*sh0*sum_i x0_i w11[i,r] + INV24*sum_i (x1[i,:].sh1) w14[i,r]
        float s1 = 0.f, s2 = 0.f;
        #pragma unroll
        for (int i = 0; i < 16; ++i) s1 = fmaf(x[i], Ae[i * 16 + r], s1);
        #pragma unroll
        for (int i = 0; i < 8; ++i) {
            const float d = x[16 + 3 * i] * s1x + x[17 + 3 * i] * s1y + x[18 + 3 * i] * s1z;
            s2 = fmaf(d, Ae[448 + i * 16 + r], s2);
        }
        atomicAdd(&sums[(size_t)src * 40 + r], INV16 * sh0 * s1 + INV24 * s2);

        if (r < 8) {
            // out1[r][m] = INV16*sh1_m*sum_i x0_i w12[i,r] + INV8*sh0*sum_i x1[i,m] w13[i,r]
            float p = 0.f, q0 = 0.f, q1 = 0.f, q2 = 0.f;
            #pragma unroll
            for (int i = 0; i < 16; ++i) p = fmaf(x[i], Ae[256 + i * 8 + r], p);
            #pragma unroll
            for (int i = 0; i < 8; ++i) {
                const float av = Ae[384 + i * 8 + r];
                q0 = fmaf(x[16 + 3 * i], av, q0);
                q1 = fmaf(x[17 + 3 * i], av, q1);
                q2 = fmaf(x[18 + 3 * i], av, q2);
            }
            const float ps = INV16 * p;
            const float qs = INV8 * sh0;
            atomicAdd(&sums[(size_t)src * 40 + 16 + 3 * r + 0], s1x * ps + qs * q0);
            atomicAdd(&sums[(size_t)src * 40 + 16 + 3 * r + 1], s1y * ps + qs * q1);
            atomicAdd(&sums[(size_t)src * 40 + 16 + 3 * r + 2], s1z * ps + qs * q2);
        }
        if (r == 0) atomicAdd(&cnts[src], 1.0f);
    }
}

// -----------------------------------------------------------------------------
// y = sums/max(cnt,1) + atom; accumulate BN statistics (wave-shuffle reduced)
// stats layout: [0..15] sum(y_j), [16..31] sum(y_j^2), [32..39] sum(|v_j|^2/3)
// -----------------------------------------------------------------------------
__global__ __launch_bounds__(256)
void finalize_stats_kernel(const float* __restrict__ sums,
                           const float* __restrict__ cnts,
                           const float* __restrict__ atom,
                           float* __restrict__ y,       // d_out
                           float* __restrict__ stats)   // [40]
{
    const int n = blockIdx.x * blockDim.x + threadIdx.x;
    float yv[40];
    if (n < N_NODES) {
        const float rinv = 1.0f / fmaxf(cnts[n], 1.0f);
        const float4* s4 = (const float4*)(sums + (size_t)n * 40);
        const float4* a4 = (const float4*)(atom + (size_t)n * 40);
        float4* y4 = (float4*)(y + (size_t)n * 40);
        #pragma unroll
        for (int r = 0; r < 10; ++r) {
            const float4 sv = s4[r];
            const float4 av = a4[r];
            float4 o;
            o.x = sv.x * rinv + av.x;
            o.y = sv.y * rinv + av.y;
            o.z = sv.z * rinv + av.z;
            o.w = sv.w * rinv + av.w;
            y4[r] = o;
            yv[r * 4 + 0] = o.x; yv[r * 4 + 1] = o.y;
            yv[r * 4 + 2] = o.z; yv[r * 4 + 3] = o.w;
        }
    } else {
        #pragma unroll
        for (int s = 0; s < 40; ++s) yv[s] = 0.0f;
    }

    float contrib[40];
    #pragma unroll
    for (int j = 0; j < 16; ++j) {
        contrib[j]      = yv[j];
        contrib[16 + j] = yv[j] * yv[j];
    }
    #pragma unroll
    for (int j = 0; j < 8; ++j) {
        const float vx = yv[16 + 3 * j], vy = yv[17 + 3 * j], vz = yv[18 + 3 * j];
        contrib[32 + j] = (vx * vx + vy * vy + vz * vz) * (1.0f / 3.0f);
    }
    #pragma unroll
    for (int s = 0; s < 40; ++s) {
        float v = contrib[s];
        #pragma unroll
        for (int off = 32; off > 0; off >>= 1) v += __shfl_xor(v, off);
        if ((threadIdx.x & 63) == 0) atomicAdd(&stats[s], v);
    }
}

// -----------------------------------------------------------------------------
// Apply batch-norm affine in place on y (= d_out)
// -----------------------------------------------------------------------------
__global__ __launch_bounds__(256)
void apply_bn_kernel(float* __restrict__ y,
                     const float* __restrict__ stats,
                     const float* __restrict__ bnw,   // [24]
                     const float* __restrict__ bnb)   // [16]
{
    const int idx = blockIdx.x * blockDim.x + threadIdx.x;
    if (idx >= N_NODES * 40) return;
    const int o = idx % 40;
    const float invN = 1.0f / (float)N_NODES;
    const float v = y[idx];
    float out;
    if (o < MUL0) {
        const float mean  = stats[o] * invN;
        const float var   = stats[16 + o] * invN - mean * mean;
        const float scale = rsqrtf(var + EPS) * bnw[o];
        out = (v - mean) * scale + bnb[o];
    } else {
        const int j = (o - 16) / 3;
        const float vn = stats[32 + j] * invN;
        out = v * (rsqrtf(vn + EPS) * bnw[16 + j]);
    }
    y[idx] = out;
}

// -----------------------------------------------------------------------------
extern "C" void kernel_launch(void* const* d_in, const int* in_sizes, int n_in,
                              void* d_out, int out_size, void* d_ws, size_t ws_size,
                              hipStream_t stream)
{
    const float* atom = (const float*)d_in[0];
    const float* ef   = (const float*)d_in[1];
    const float* esh  = (const float*)d_in[2];
    const int*   eidx = (const int*)d_in[3];
    const float* W1   = (const float*)d_in[4];
    const float* b1   = (const float*)d_in[5];
    const float* W2   = (const float*)d_in[6];
    const float* b2   = (const float*)d_in[7];
    const float* bnw  = (const float*)d_in[8];
    const float* bnb  = (const float*)d_in[9];
    float* out = (float*)d_out;

    float* sums  = (float*)d_ws;               // N_NODES*40
    float* cnts  = sums + (size_t)N_NODES * 40; // N_NODES
    float* stats = cnts + N_NODES;             // 40

    const int* e_dst = eidx;
    const int* e_src = eidx + N_EDGES;

    hipMemsetAsync(d_ws, 0, ((size_t)N_NODES * 40 + N_NODES + 40) * sizeof(float), stream);

    fused_edge_kernel<<<N_EDGES / BM, THREADS, 0, stream>>>(
        atom, ef, esh, e_dst, e_src, W1, b1, W2, b2, sums, cnts);

    finalize_stats_kernel<<<(N_NODES + 255) / 256, 256, 0, stream>>>(
        sums, cnts, atom, out, stats);

    apply_bn_kernel<<<(N_NODES * 40 + 255) / 256, 256, 0, stream>>>(
        out, stats, bnw, bnb);
}

// Round 2
// 167.975 us; speedup vs baseline: 1.8751x; 1.8751x over previous
//
#include <hip/hip_runtime.h>

#define N_NODES 10000
#define N_EDGES 160000
#define MUL0 16
#define MUL1 8
#define H_EDGE 64
#define W_NUMEL 576
#define EPS 1e-5f

#define BM 64          // edges per block
#define THREADS 256

#define INV16 0.25f
#define INV24 0.20412414523193154f   // 1/sqrt(24)
#define INV8  0.3535533905932738f    // 1/sqrt(8)

typedef __attribute__((ext_vector_type(8))) short bf16x8;
typedef __attribute__((ext_vector_type(4))) short bf16x4;
typedef __attribute__((ext_vector_type(4))) float f32x4;

__device__ __forceinline__ unsigned short f2bf(float x) {
    union { float f; unsigned int u; } c; c.f = x;
    unsigned int r = c.u + 0x7fffu + ((c.u >> 16) & 1u);   // RNE
    return (unsigned short)(r >> 16);
}

// fragment k-index for 16x16x32 bf16: k = 32*ks + 16*(j>>2) + 4*(lane>>4) + (j&3)

// -----------------------------------------------------------------------------
// Prep: pack W1^T and W2^T into per-lane MFMA A-fragment order (bf16).
// W1F[mt(4)][ks(2)][lane(64)][j(8)], W2F[nt(36)][ks(2)][lane(64)][j(8)]
// A[row=16*t+(l&15)][k] with k = 32*ks + 16*(j>>2) + 4*(l>>4) + (j&3);
// A = W^T so A[row][k] = W[k][row].
// -----------------------------------------------------------------------------
__global__ __launch_bounds__(256)
void prep_frags(const float* __restrict__ W1, const float* __restrict__ W2,
                unsigned short* __restrict__ W1F, unsigned short* __restrict__ W2F)
{
    int idx = blockIdx.x * 256 + threadIdx.x;
    if (idx >= 4096 + 36864) return;
    if (idx < 4096) {
        const int j = idx & 7, l = (idx >> 3) & 63, ks = (idx >> 9) & 1, mt = idx >> 10;
        const int k = 32 * ks + 16 * (j >> 2) + 4 * (l >> 4) + (j & 3);
        const int col = 16 * mt + (l & 15);
        W1F[idx] = f2bf(W1[k * 64 + col]);
    } else {
        const int i2 = idx - 4096;
        const int j = i2 & 7, l = (i2 >> 3) & 63, ks = (i2 >> 9) & 1, nt = i2 >> 10;
        const int k = 32 * ks + 16 * (j >> 2) + 4 * (l >> 4) + (j & 3);
        const int col = 16 * nt + (l & 15);
        W2F[i2] = f2bf(W2[k * 576 + col]);
    }
}

// -----------------------------------------------------------------------------
// Fused edge kernel (MFMA): h^T = relu(W1^T ef^T + b1), w^T = W2^T h^T + b2,
// TP + atomic scatter.
// -----------------------------------------------------------------------------
__global__ __launch_bounds__(THREADS, 2)
void fused_edge_kernel(const float* __restrict__ atom,   // [N_NODES*40]
                       const float* __restrict__ ef,     // [N_EDGES*64]
                       const float* __restrict__ esh,    // [N_EDGES*4]
                       const int*   __restrict__ e_dst,
                       const int*   __restrict__ e_src,
                       const unsigned short* __restrict__ W1F,
                       const float* __restrict__ b1,
                       const unsigned short* __restrict__ W2F,
                       const float* __restrict__ b2,
                       float* __restrict__ sums,         // [N_NODES*40]
                       float* __restrict__ cnts)         // [N_NODES]
{
    __shared__ unsigned short ef_lds[64 * 64];   // [edge][f] bf16, XOR-swizzled rows
    __shared__ unsigned short h_lds[64 * 64];    // [edge][n] bf16, XOR-swizzled rows
    __shared__ float W_lds[576 * 18];            // w^T slice [nw][16 edges + pad]

    const int tid = threadIdx.x;
    const int l   = tid & 63;        // lane
    const int wv  = tid >> 6;        // wave 0..3
    const int e0  = blockIdx.x * BM;
    const int h4  = l >> 4;          // 0..3
    const int e16 = l & 15;

    // ---- stage ef tile -> LDS bf16 (swizzled) ----
    {
        const int edge = tid >> 2;           // 0..63
        const int fq   = tid & 3;
        #pragma unroll
        for (int ii = 0; ii < 4; ++ii) {
            const int f = fq * 16 + ii * 4;
            const float4 v = *(const float4*)(ef + (size_t)(e0 + edge) * 64 + f);
            bf16x4 p;
            p[0] = (short)f2bf(v.x); p[1] = (short)f2bf(v.y);
            p[2] = (short)f2bf(v.z); p[3] = (short)f2bf(v.w);
            const int addr = ((edge << 7) + (f << 1)) ^ ((edge & 7) << 4);
            *(bf16x4*)((char*)ef_lds + addr) = p;
        }
    }
    __syncthreads();

    // ---- GEMM1: wave wv computes h^T cols (edges) [16wv,16wv+16), all 64 rows ----
    {
        const int edge = 16 * wv + e16;
        bf16x8 bE[2];
        #pragma unroll
        for (int ks = 0; ks < 2; ++ks) {
            const int f0 = 32 * ks + 4 * h4;
            const int a0 = ((edge << 7) + (f0 << 1)) ^ ((edge & 7) << 4);
            const int a1 = ((edge << 7) + ((f0 + 16) << 1)) ^ ((edge & 7) << 4);
            bf16x4 lo = *(const bf16x4*)((const char*)ef_lds + a0);
            bf16x4 hi = *(const bf16x4*)((const char*)ef_lds + a1);
            bf16x8 b;
            b[0]=lo[0]; b[1]=lo[1]; b[2]=lo[2]; b[3]=lo[3];
            b[4]=hi[0]; b[5]=hi[1]; b[6]=hi[2]; b[7]=hi[3];
            bE[ks] = b;
        }
        #pragma unroll
        for (int mti = 0; mti < 4; ++mti) {
            f32x4 a = *(const f32x4*)(b1 + 16 * mti + 4 * h4);
            #pragma unroll
            for (int ks = 0; ks < 2; ++ks) {
                const bf16x8 aW = *(const bf16x8*)(W1F + ((size_t)(mti * 2 + ks) * 64 + l) * 8);
                a = __builtin_amdgcn_mfma_f32_16x16x32_bf16(aW, bE[ks], a, 0, 0, 0);
            }
            bf16x4 hw;
            #pragma unroll
            for (int r = 0; r < 4; ++r) hw[r] = (short)f2bf(fmaxf(a[r], 0.0f));
            const int n0 = 16 * mti + 4 * h4;
            const int addr = ((edge << 7) + (n0 << 1)) ^ ((edge & 7) << 4);
            *(bf16x4*)((char*)h_lds + addr) = hw;
        }
    }
    __syncthreads();

    // ---- GEMM2: wave wv owns N-tiles nt = 9wv..9wv+8, all 4 edge tiles ----
    bf16x8 bH[4][2];
    #pragma unroll
    for (int mt = 0; mt < 4; ++mt) {
        const int edge = 16 * mt + e16;
        #pragma unroll
        for (int ks = 0; ks < 2; ++ks) {
            const int f0 = 32 * ks + 4 * h4;
            const int a0 = ((edge << 7) + (f0 << 1)) ^ ((edge & 7) << 4);
            const int a1 = ((edge << 7) + ((f0 + 16) << 1)) ^ ((edge & 7) << 4);
            bf16x4 lo = *(const bf16x4*)((const char*)h_lds + a0);
            bf16x4 hi = *(const bf16x4*)((const char*)h_lds + a1);
            bf16x8 b;
            b[0]=lo[0]; b[1]=lo[1]; b[2]=lo[2]; b[3]=lo[3];
            b[4]=hi[0]; b[5]=hi[1]; b[6]=hi[2]; b[7]=hi[3];
            bH[mt][ks] = b;
        }
    }

    f32x4 acc[9][4];
    #pragma unroll
    for (int t = 0; t < 9; ++t) {
        const int nt = 9 * wv + t;
        const f32x4 bias = *(const f32x4*)(b2 + 16 * nt + 4 * h4);
        #pragma unroll
        for (int mt = 0; mt < 4; ++mt) acc[t][mt] = bias;
        #pragma unroll
        for (int ks = 0; ks < 2; ++ks) {
            const bf16x8 aW = *(const bf16x8*)(W2F + ((size_t)(nt * 2 + ks) * 64 + l) * 8);
            #pragma unroll
            for (int mt = 0; mt < 4; ++mt)
                acc[t][mt] = __builtin_amdgcn_mfma_f32_16x16x32_bf16(aW, bH[mt][ks], acc[t][mt], 0, 0, 0);
        }
    }

    // ---- TP + scatter per 16-edge tile ----
    #pragma unroll
    for (int mt = 0; mt < 4; ++mt) {
        __syncthreads();
        #pragma unroll
        for (int t = 0; t < 9; ++t) {
            #pragma unroll
            for (int r = 0; r < 4; ++r)
                W_lds[(size_t)(144 * wv + 16 * t + 4 * h4 + r) * 18 + e16] = acc[t][mt][r];
        }
        __syncthreads();

        const int r  = tid & 15;
        const int el = tid >> 4;                   // 0..15
        const int e  = e0 + 16 * mt + el;
        const int dst = e_dst[e];
        const int src = e_src[e];
        const float* x = atom + (size_t)dst * 40;
        const float sh0 = esh[e * 4 + 0];
        const float s1x = esh[e * 4 + 1];
        const float s1y = esh[e * 4 + 2];
        const float s1z = esh[e * 4 + 3];
        #define WW(nw) W_lds[(nw) * 18 + el]

        float s1 = 0.f, s2 = 0.f;
        #pragma unroll
        for (int i = 0; i < 16; ++i) s1 = fmaf(x[i], WW(i * 16 + r), s1);
        #pragma unroll
        for (int i = 0; i < 8; ++i) {
            const float d = x[16 + 3 * i] * s1x + x[17 + 3 * i] * s1y + x[18 + 3 * i] * s1z;
            s2 = fmaf(d, WW(448 + i * 16 + r), s2);
        }
        atomicAdd(&sums[(size_t)src * 40 + r], INV16 * sh0 * s1 + INV24 * s2);

        if (r < 8) {
            float p = 0.f, q0 = 0.f, q1 = 0.f, q2 = 0.f;
            #pragma unroll
            for (int i = 0; i < 16; ++i) p = fmaf(x[i], WW(256 + i * 8 + r), p);
            #pragma unroll
            for (int i = 0; i < 8; ++i) {
                const float av = WW(384 + i * 8 + r);
                q0 = fmaf(x[16 + 3 * i], av, q0);
                q1 = fmaf(x[17 + 3 * i], av, q1);
                q2 = fmaf(x[18 + 3 * i], av, q2);
            }
            const float ps = INV16 * p;
            const float qs = INV8 * sh0;
            atomicAdd(&sums[(size_t)src * 40 + 16 + 3 * r + 0], s1x * ps + qs * q0);
            atomicAdd(&sums[(size_t)src * 40 + 16 + 3 * r + 1], s1y * ps + qs * q1);
            atomicAdd(&sums[(size_t)src * 40 + 16 + 3 * r + 2], s1z * ps + qs * q2);
        }
        if (r == 0) atomicAdd(&cnts[src], 1.0f);
        #undef WW
    }
}

// -----------------------------------------------------------------------------
// y = sums/max(cnt,1) + atom; accumulate BN statistics (wave-shuffle reduced)
// -----------------------------------------------------------------------------
__global__ __launch_bounds__(256)
void finalize_stats_kernel(const float* __restrict__ sums,
                           const float* __restrict__ cnts,
                           const float* __restrict__ atom,
                           float* __restrict__ y,
                           float* __restrict__ stats)
{
    const int n = blockIdx.x * blockDim.x + threadIdx.x;
    float yv[40];
    if (n < N_NODES) {
        const float rinv = 1.0f / fmaxf(cnts[n], 1.0f);
        const float4* s4 = (const float4*)(sums + (size_t)n * 40);
        const float4* a4 = (const float4*)(atom + (size_t)n * 40);
        float4* y4 = (float4*)(y + (size_t)n * 40);
        #pragma unroll
        for (int r = 0; r < 10; ++r) {
            const float4 sv = s4[r];
            const float4 av = a4[r];
            float4 o;
            o.x = sv.x * rinv + av.x;
            o.y = sv.y * rinv + av.y;
            o.z = sv.z * rinv + av.z;
            o.w = sv.w * rinv + av.w;
            y4[r] = o;
            yv[r * 4 + 0] = o.x; yv[r * 4 + 1] = o.y;
            yv[r * 4 + 2] = o.z; yv[r * 4 + 3] = o.w;
        }
    } else {
        #pragma unroll
        for (int s = 0; s < 40; ++s) yv[s] = 0.0f;
    }

    float contrib[40];
    #pragma unroll
    for (int j = 0; j < 16; ++j) {
        contrib[j]      = yv[j];
        contrib[16 + j] = yv[j] * yv[j];
    }
    #pragma unroll
    for (int j = 0; j < 8; ++j) {
        const float vx = yv[16 + 3 * j], vy = yv[17 + 3 * j], vz = yv[18 + 3 * j];
        contrib[32 + j] = (vx * vx + vy * vy + vz * vz) * (1.0f / 3.0f);
    }
    #pragma unroll
    for (int s = 0; s < 40; ++s) {
        float v = contrib[s];
        #pragma unroll
        for (int off = 32; off > 0; off >>= 1) v += __shfl_xor(v, off);
        if ((threadIdx.x & 63) == 0) atomicAdd(&stats[s], v);
    }
}

__global__ __launch_bounds__(256)
void apply_bn_kernel(float* __restrict__ y,
                     const float* __restrict__ stats,
                     const float* __restrict__ bnw,
                     const float* __restrict__ bnb)
{
    const int idx = blockIdx.x * blockDim.x + threadIdx.x;
    if (idx >= N_NODES * 40) return;
    const int o = idx % 40;
    const float invN = 1.0f / (float)N_NODES;
    const float v = y[idx];
    float out;
    if (o < MUL0) {
        const float mean  = stats[o] * invN;
        const float var   = stats[16 + o] * invN - mean * mean;
        const float scale = rsqrtf(var + EPS) * bnw[o];
        out = (v - mean) * scale + bnb[o];
    } else {
        const int j = (o - 16) / 3;
        const float vn = stats[32 + j] * invN;
        out = v * (rsqrtf(vn + EPS) * bnw[16 + j]);
    }
    y[idx] = out;
}

// -----------------------------------------------------------------------------
extern "C" void kernel_launch(void* const* d_in, const int* in_sizes, int n_in,
                              void* d_out, int out_size, void* d_ws, size_t ws_size,
                              hipStream_t stream)
{
    const float* atom = (const float*)d_in[0];
    const float* ef   = (const float*)d_in[1];
    const float* esh  = (const float*)d_in[2];
    const int*   eidx = (const int*)d_in[3];
    const float* W1   = (const float*)d_in[4];
    const float* b1   = (const float*)d_in[5];
    const float* W2   = (const float*)d_in[6];
    const float* b2   = (const float*)d_in[7];
    const float* bnw  = (const float*)d_in[8];
    const float* bnb  = (const float*)d_in[9];
    float* out = (float*)d_out;

    float* sums  = (float*)d_ws;                       // N_NODES*40
    float* cnts  = sums + (size_t)N_NODES * 40;        // N_NODES
    float* stats = cnts + N_NODES;                     // 40
    unsigned short* W1F = (unsigned short*)(stats + 40);   // 4096 bf16
    unsigned short* W2F = W1F + 4096;                      // 36864 bf16

    const int* e_dst = eidx;
    const int* e_src = eidx + N_EDGES;

    hipMemsetAsync(d_ws, 0, ((size_t)N_NODES * 40 + N_NODES + 40) * sizeof(float), stream);

    prep_frags<<<(4096 + 36864 + 255) / 256, 256, 0, stream>>>(W1, W2, W1F, W2F);

    fused_edge_kernel<<<N_EDGES / BM, THREADS, 0, stream>>>(
        atom, ef, esh, e_dst, e_src, W1F, b1, W2F, b2, sums, cnts);

    finalize_stats_kernel<<<(N_NODES + 255) / 256, 256, 0, stream>>>(
        sums, cnts, atom, out, stats);

    apply_bn_kernel<<<(N_NODES * 40 + 255) / 256, 256, 0, stream>>>(
        out, stats, bnw, bnb);
}